// Round 6
// baseline (386.815 us; speedup 1.0000x reference)
//
#include <hip/hip_runtime.h>
#include <cstddef>

#define B_ROWS 8192
#define DIM    1024
#define NSESS  32
#define MT     128       // rows per M-tile
#define NTILE  128       // cols per N-tile
#define BK     64        // fp32 per K-chunk per phase = 2 MFMA k-steps
#define KITERS (DIM / BK)   // 16
#define TPE    3         // m-tiles per expert (validated: max expert count <= 384)
#define LROW   72        // shorts per LDS row: 64 bf16 + 8 pad = 144 B (16B-mult)
#define TSZ    (MT * LROW)
#define NXCD   8
#define EPX    (NSESS / NXCD)        // experts per XCD = 4
#define BPE    (TPE * (DIM / NTILE)) // blocks per expert = 24

typedef __attribute__((ext_vector_type(8))) short short8;
typedef __attribute__((ext_vector_type(4))) float floatx4;
typedef __attribute__((ext_vector_type(4))) int intx4;
typedef __attribute__((ext_vector_type(2))) unsigned int uintx2;

// RNE fp32->bf16 for two values, packed into one dword via v_perm_b32.
__device__ __forceinline__ unsigned pack_bf16_2(float fa, float fb) {
  unsigned a = __builtin_bit_cast(unsigned, fa);
  unsigned b = __builtin_bit_cast(unsigned, fb);
  a += 0x7fffu + ((a >> 16) & 1u);
  b += 0x7fffu + ((b >> 16) & 1u);
  return __builtin_amdgcn_perm(b, a, 0x07060302u); // low = bf16(fa), high = bf16(fb)
}

// Round-11 (post-mortem r10: FIVE configs {fetch 206/90MB} x {occ 14/26%} x
// {demand 670/390MB} x {tile 128^2/256^2} ALL land 131-138us. Bytes, occupancy,
// locality each individually refuted; implied "service rate" tracked the byte
// cut 4.9->2.9TB/s, killing the BW model. The one never-varied axis: pipeline
// DEPTH — every round drains chunk k+1's loads at the end of phase k (1-phase
// in-flight). If the limiter is L2-miss/L3 round-trip LATENCY, time = KITERS x
// latency, insensitive to everything tried. This round, on the best base (r6
// dbuf, 131us, 1 barrier/phase), changes ONLY depth:
//  - TWO register prefetch sets; set parity == chunk parity == LDS buffer
//    parity. Loads issued 2 full COMPUTE phases before their CVTWRITE drain;
//    the drain waits only its own set (compiler emits counted vmcnt, the other
//    set's 16 loads stay outstanding across both barriers).
//  - 32-bit byte offsets (r8, saves 16 VGPR); k0+k1 B-loads before sidx scan.
//  - __launch_bounds__(256,2): peak ~220 regs in 256 cap, no spill
//    (canary: WRITE_SIZE ~39MB). LDS 75264 -> 2 blocks/CU (r6 level; r8
//    proved occupancy is not the lever).
//  - keep: XCD-clustered decode, 16-lane x 16B = 256B staging segments,
//    bf16 LDS +16B row pad, ranked compaction, masked epilogue.
__global__ __launch_bounds__(256, 2) void gemm_kernel(
    const float* __restrict__ x, const float* __restrict__ W,
    const float* __restrict__ bias, const int* __restrict__ sidx,
    float* __restrict__ out)
{
  __shared__ __align__(16) short As0[TSZ], As1[TSZ];
  __shared__ __align__(16) short Bs0[TSZ], Bs1[TSZ];
  __shared__ int row_ids[MT];
  __shared__ int psum[256];

  // ---- XCD-clustered decode ----
  const int hw    = blockIdx.x;          // 0..767, assumed XCD = hw % 8
  const int xcd   = hw & (NXCD - 1);
  const int r     = hw >> 3;             // 0..95: within-XCD sequence
  const int s     = xcd * EPX + (r / BPE);   // expert, clustered per XCD
  const int rr    = r % BPE;             // 0..23
  const int ntile = rr / TPE;            // 0..7 (W slice shared by 3 mtiles)
  const int mtile = rr % TPE;
  const int tid   = threadIdx.x;

  const int lane = tid & 63;
  const int wv   = tid >> 6;            // wave id
  const int wm   = wv >> 1;             // 0..1 : 64-row half
  const int wn   = wv & 1;              // 0..1 : 64-col half
  const int fr   = lane & 15;           // fragment row within 16
  const int kg   = lane >> 4;           // fragment k-group (k = kg*8 + j)

  // ---- staging geometry: instr j covers tile-rows srow+j*4, 256 B each ----
  const int srow   = wv * 32 + (lane >> 4);
  const int schunk = lane & 15;

  // B byte-offsets + k0/k1 B-loads issued before the sidx scan.
  unsigned boff[8];
  floatx4 wr0[8], wr1[8];
  {
    const unsigned wbyte =
        (unsigned)(((size_t)s * DIM * DIM + (size_t)(ntile * NTILE) * DIM) * 4u);
#pragma unroll
    for (int j = 0; j < 8; ++j) {
      const int tr = srow + j * 4;
      boff[j] = wbyte + (unsigned)((tr * DIM + schunk * 4) * 4);
      wr0[j] = *(const floatx4*)((const char*)W + boff[j]);
    }
#pragma unroll
    for (int j = 0; j < 8; ++j)
      wr1[j] = *(const floatx4*)((const char*)W + boff[j] + (BK * 4));
  }

  // ---- ranked compaction: rows with sidx==s, ranks [mtile*128, +128) ----
  const intx4* sv = (const intx4*)(sidx + tid * 32);
  int c = 0;
#pragma unroll
  for (int j = 0; j < 8; ++j) {
    const intx4 v = sv[j];
#pragma unroll
    for (int e = 0; e < 4; ++e) c += (v[e] == s);
  }
  psum[tid] = c;
  __syncthreads();
#pragma unroll
  for (int d = 1; d < 256; d <<= 1) {
    const int mine = psum[tid];
    const int add  = (tid >= d) ? psum[tid - d] : 0;
    __syncthreads();
    psum[tid] = mine + add;
    __syncthreads();
  }
  const int total = psum[255];
  const int nrows = (total - mtile * MT) < 0 ? 0
                  : ((total - mtile * MT) > MT ? MT : (total - mtile * MT));
  if (nrows == 0) return;               // uniform across block
  const int base_rank = psum[tid] - c;

  if (tid < MT) row_ids[tid] = -1;
  __syncthreads();
  {
    int r2 = base_rank;
    const int lo = mtile * MT, hi = lo + MT;
#pragma unroll
    for (int j = 0; j < 8; ++j) {
      const intx4 v = sv[j];
#pragma unroll
      for (int e = 0; e < 4; ++e) {
        if (v[e] == s) {
          if (r2 >= lo && r2 < hi) row_ids[r2 - lo] = tid * 32 + 4 * j + e;
          ++r2;
        }
      }
    }
  }
  __syncthreads();

  unsigned aoff[8];
  floatx4 xr0[8], xr1[8];
#pragma unroll
  for (int j = 0; j < 8; ++j) {
    int ar = row_ids[srow + j * 4];
    if (ar < 0) ar = 0;                 // finite dummy; epilogue masks rows >= nrows
    aoff[j] = (unsigned)((ar * DIM + schunk * 4) * 4);
    xr0[j] = *(const floatx4*)((const char*)x + aoff[j]);            // k0 A
  }
#pragma unroll
  for (int j = 0; j < 8; ++j)
    xr1[j] = *(const floatx4*)((const char*)x + aoff[j] + (BK * 4)); // k1 A

  floatx4 acc[4][4] = {};

#define LOADSET(XR, WR, KB)                                                    \
  {                                                                            \
    _Pragma("unroll")                                                          \
    for (int j = 0; j < 8; ++j) {                                              \
      XR[j] = *(const floatx4*)((const char*)x + aoff[j] + (KB) * (BK * 4));   \
      WR[j] = *(const floatx4*)((const char*)W + boff[j] + (KB) * (BK * 4));   \
    }                                                                          \
  }

#define CVTWRITE(XR, WR, AS, BS)                                               \
  {                                                                            \
    _Pragma("unroll")                                                          \
    for (int j = 0; j < 8; ++j) {                                              \
      const int off = (srow + j * 4) * LROW + schunk * 4;                      \
      uintx2 ua = { pack_bf16_2(XR[j][0], XR[j][1]),                           \
                    pack_bf16_2(XR[j][2], XR[j][3]) };                         \
      uintx2 ub = { pack_bf16_2(WR[j][0], WR[j][1]),                           \
                    pack_bf16_2(WR[j][2], WR[j][3]) };                         \
      *(uintx2*)&AS[off] = ua;                                                 \
      *(uintx2*)&BS[off] = ub;                                                 \
    }                                                                          \
  }

#define COMPUTE(AS, BS)                                                        \
  {                                                                            \
    _Pragma("unroll")                                                          \
    for (int s2 = 0; s2 < 2; ++s2) {                                           \
      short8 fb[4];                                                            \
      _Pragma("unroll")                                                        \
      for (int i = 0; i < 4; ++i)                                              \
        fb[i] = *(const short8*)&BS[(wn * 64 + i * 16 + fr) * LROW + s2 * 32 + kg * 8]; \
      _Pragma("unroll")                                                        \
      for (int mi = 0; mi < 4; ++mi) {                                         \
        const short8 fa = *(const short8*)&AS[(wm * 64 + mi * 16 + fr) * LROW + s2 * 32 + kg * 8]; \
        _Pragma("unroll")                                                      \
        for (int ni = 0; ni < 4; ++ni)                                         \
          acc[mi][ni] = __builtin_amdgcn_mfma_f32_16x16x32_bf16(               \
              fa, fb[ni], acc[mi][ni], 0, 0, 0);                               \
      }                                                                        \
    }                                                                          \
  }

  // prologue: k0 (set0) -> LDS0. set1 (k1) stays in flight.
  CVTWRITE(xr0, wr0, As0, Bs0);
  __syncthreads();

  // Pair loop: even chunks use set0/LDS0, odd chunks set1/LDS1.
  // Each set's loads are issued 2 COMPUTE phases before their CVTWRITE drain.
  for (int kb = 0; kb < KITERS; kb += 2) {
    // phase A: compute k(kb) from LDS0; refill set0 with k(kb+2);
    //          stage set1 (k(kb+1), issued one pair ago) into LDS1
    if (kb + 2 < KITERS) LOADSET(xr0, wr0, kb + 2);
    COMPUTE(As0, Bs0);
    CVTWRITE(xr1, wr1, As1, Bs1);     // counted vmcnt: waits set1 only
    __syncthreads();

    // phase B: compute k(kb+1) from LDS1; refill set1 with k(kb+3);
    //          stage set0 (k(kb+2)) into LDS0
    if (kb + 3 < KITERS) LOADSET(xr1, wr1, kb + 3);
    COMPUTE(As1, Bs1);
    if (kb + 2 < KITERS) {
      CVTWRITE(xr0, wr0, As0, Bs0);   // counted vmcnt: waits set0 only
    }
    __syncthreads();
  }

#undef LOADSET
#undef CVTWRITE
#undef COMPUTE

  // epilogue: D row = (lane>>4)*4 + reg, D col = lane&15
  const int col0 = ntile * NTILE + wn * 64;
#pragma unroll
  for (int ni = 0; ni < 4; ++ni) {
    const int n = col0 + ni * 16 + fr;
    const float bv = bias[s * DIM + n];
#pragma unroll
    for (int mi = 0; mi < 4; ++mi) {
      const int mbase = wm * 64 + mi * 16 + kg * 4;
#pragma unroll
      for (int rr2 = 0; rr2 < 4; ++rr2) {
        const int ml = mbase + rr2;
        if (ml < nrows) {
          const int orow = row_ids[ml];
          out[(size_t)orow * DIM + n] = acc[mi][ni][rr2] + bv;
        }
      }
    }
  }
}

extern "C" void kernel_launch(void* const* d_in, const int* in_sizes, int n_in,
                              void* d_out, int out_size, void* d_ws, size_t ws_size,
                              hipStream_t stream) {
  const float* x    = (const float*)d_in[0];
  const float* W    = (const float*)d_in[1];
  const float* b    = (const float*)d_in[2];
  const int*   sidx = (const int*)d_in[3];
  float* out = (float*)d_out;
  (void)d_ws; (void)ws_size;  // OFF-LIMITS: any ws touch => 512MiB re-poison
                              // fill (~80us) per iteration (r9 post-mortem)

  hipLaunchKernelGGL(gemm_kernel, dim3(NSESS * TPE * (DIM / NTILE)), dim3(256),
                     0, stream, x, W, b, sidx, out);
}

// Round 7
// 273.053 us; speedup vs baseline: 1.4166x; 1.4166x over previous
//
#include <hip/hip_runtime.h>
#include <cstddef>

#define B_ROWS 8192
#define DIM    1024
#define NSESS  32
#define MT     128       // rows per M-tile
#define NTILE  128       // cols per N-tile
#define BK     64        // fp32 per K-chunk per iter = 2 MFMA k-steps
#define KITERS (DIM / BK)   // 16
#define TPE    3         // m-tiles per expert (validated: max expert count <= 384)
#define LROW   72        // shorts per LDS row: 64 bf16 + 8 pad = 144 B (16B-mult)
#define TSZ    (MT * LROW)
#define NXCD   8
#define EPX    (NSESS / NXCD)        // experts per XCD = 4
#define BPE    (TPE * (DIM / NTILE)) // blocks per expert = 24

typedef __attribute__((ext_vector_type(8))) short short8;
typedef __attribute__((ext_vector_type(4))) float floatx4;
typedef __attribute__((ext_vector_type(4))) int intx4;
typedef __attribute__((ext_vector_type(2))) unsigned int uintx2;

// RNE fp32->bf16 for two values, packed into one dword via v_perm_b32.
__device__ __forceinline__ unsigned pack_bf16_2(float fa, float fb) {
  unsigned a = __builtin_bit_cast(unsigned, fa);
  unsigned b = __builtin_bit_cast(unsigned, fb);
  a += 0x7fffu + ((a >> 16) & 1u);
  b += 0x7fffu + ((b >> 16) & 1u);
  return __builtin_amdgcn_perm(b, a, 0x07060302u); // low = bf16(fa), high = bf16(fb)
}

// Round-12 (post-mortems r6-r11: bytes, occupancy, L2 locality, phase count,
// block count, pipeline depth — each perturbed, time pinned 131-138us. The
// ONE config-invariant in-kernel cost: the epilogue. Old epilogue = 64 scalar
// dword stores/thread; each wave-instr scatters 16 rows x 64-B PARTIAL-line
// segments into row_ids-scattered 4KB lines -> ~10M store instrs, 610k
// half-line RMW segments (FETCH always ~16MB above W+x demand = RMW reads).
// Meanwhile MfmaUtil*dur = 8.2us == full-rate MFMA time and VALUBusy*dur ==
// counted VALU work: compute runs at speed; the rest is the store drain.
// This round keeps the proven 131-us K-loop VERBATIM and only replaces the
// epilogue: acc -> LDS transpose (alias As0, 4 passes of 32 rows, [32][132]
// f32, bias folded) -> global_store_dwordx4 with 32 lanes per FULL 512-B row
// segment (4 full lines, no RMW): 16 vector stores/thread vs 64 scalar.
__global__ __launch_bounds__(256, 2) void gemm_kernel(
    const float* __restrict__ x, const float* __restrict__ W,
    const float* __restrict__ bias, const int* __restrict__ sidx,
    float* __restrict__ out)
{
  __shared__ __align__(16) short As0[TSZ], As1[TSZ];
  __shared__ __align__(16) short Bs0[TSZ], Bs1[TSZ];
  __shared__ int row_ids[MT];
  __shared__ int psum[256];

  // ---- XCD-clustered decode ----
  const int hw    = blockIdx.x;          // 0..767, assumed XCD = hw % 8
  const int xcd   = hw & (NXCD - 1);
  const int r     = hw >> 3;             // 0..95: within-XCD sequence
  const int s     = xcd * EPX + (r / BPE);   // expert, clustered per XCD
  const int rr    = r % BPE;             // 0..23
  const int ntile = rr / TPE;            // 0..7 (W slice shared by 3 mtiles)
  const int mtile = rr % TPE;
  const int tid   = threadIdx.x;

  // ---- ranked compaction: rows with sidx==s, ranks [mtile*128, +128) ----
  const intx4* sv = (const intx4*)(sidx + tid * 32);
  int c = 0;
#pragma unroll
  for (int j = 0; j < 8; ++j) {
    const intx4 v = sv[j];
#pragma unroll
    for (int e = 0; e < 4; ++e) c += (v[e] == s);
  }
  psum[tid] = c;
  __syncthreads();
#pragma unroll
  for (int d = 1; d < 256; d <<= 1) {
    const int mine = psum[tid];
    const int add  = (tid >= d) ? psum[tid - d] : 0;
    __syncthreads();
    psum[tid] = mine + add;
    __syncthreads();
  }
  const int total = psum[255];
  const int nrows = (total - mtile * MT) < 0 ? 0
                  : ((total - mtile * MT) > MT ? MT : (total - mtile * MT));
  if (nrows == 0) return;               // uniform across block
  const int base_rank = psum[tid] - c;

  if (tid < MT) row_ids[tid] = -1;
  __syncthreads();
  {
    int r2 = base_rank;
    const int lo = mtile * MT, hi = lo + MT;
#pragma unroll
    for (int j = 0; j < 8; ++j) {
      const intx4 v = sv[j];
#pragma unroll
      for (int e = 0; e < 4; ++e) {
        if (v[e] == s) {
          if (r2 >= lo && r2 < hi) row_ids[r2 - lo] = tid * 32 + 4 * j + e;
          ++r2;
        }
      }
    }
  }
  __syncthreads();

  const int lane = tid & 63;
  const int wv   = tid >> 6;            // wave id
  const int wm   = wv >> 1;             // 0..1 : 64-row half
  const int wn   = wv & 1;              // 0..1 : 64-col half
  const int fr   = lane & 15;           // fragment row within 16
  const int kg   = lane >> 4;           // fragment k-group (k = kg*8 + j)

  // ---- staging geometry: instr j covers tile-rows srow+j*4, 256 B each ----
  const int srow   = wv * 32 + (lane >> 4);
  const int schunk = lane & 15;

  const float* apt[8];
  const float* bpt[8];
#pragma unroll
  for (int j = 0; j < 8; ++j) {
    const int tr = srow + j * 4;
    int ar = row_ids[tr];
    if (ar < 0) ar = 0;                 // finite dummy; epilogue masks rows >= nrows
    apt[j] = x + (size_t)ar * DIM + schunk * 4;
    bpt[j] = W + (size_t)s * DIM * DIM + (size_t)(ntile * NTILE + tr) * DIM + schunk * 4;
  }

  floatx4 xreg[8], wreg[8];
  floatx4 acc[4][4] = {};

#define LOADREGS(KB)                                                           \
  {                                                                            \
    _Pragma("unroll")                                                          \
    for (int j = 0; j < 8; ++j) {                                              \
      xreg[j] = *(const floatx4*)(apt[j] + (KB) * BK);                         \
      wreg[j] = *(const floatx4*)(bpt[j] + (KB) * BK);                         \
    }                                                                          \
  }

#define CVTWRITE(AS, BS)                                                       \
  {                                                                            \
    _Pragma("unroll")                                                          \
    for (int j = 0; j < 8; ++j) {                                              \
      const int off = (srow + j * 4) * LROW + schunk * 4;                      \
      uintx2 ua = { pack_bf16_2(xreg[j][0], xreg[j][1]),                       \
                    pack_bf16_2(xreg[j][2], xreg[j][3]) };                     \
      uintx2 ub = { pack_bf16_2(wreg[j][0], wreg[j][1]),                       \
                    pack_bf16_2(wreg[j][2], wreg[j][3]) };                     \
      *(uintx2*)&AS[off] = ua;                                                 \
      *(uintx2*)&BS[off] = ub;                                                 \
    }                                                                          \
  }

#define COMPUTE(AS, BS)                                                        \
  {                                                                            \
    _Pragma("unroll")                                                          \
    for (int s2 = 0; s2 < 2; ++s2) {                                           \
      short8 fa[4], fb[4];                                                     \
      _Pragma("unroll")                                                        \
      for (int i = 0; i < 4; ++i) {                                            \
        fa[i] = *(const short8*)&AS[(wm * 64 + i * 16 + fr) * LROW + s2 * 32 + kg * 8]; \
        fb[i] = *(const short8*)&BS[(wn * 64 + i * 16 + fr) * LROW + s2 * 32 + kg * 8]; \
      }                                                                        \
      _Pragma("unroll")                                                        \
      for (int mi = 0; mi < 4; ++mi)                                           \
        _Pragma("unroll")                                                      \
        for (int ni = 0; ni < 4; ++ni)                                         \
          acc[mi][ni] = __builtin_amdgcn_mfma_f32_16x16x32_bf16(               \
              fa[mi], fb[ni], acc[mi][ni], 0, 0, 0);                           \
    }                                                                          \
  }

  // prologue: stage kb=0 into buffer 0
  LOADREGS(0);
  CVTWRITE(As0, Bs0);
  __syncthreads();

  for (int kb = 0; kb < KITERS; kb += 2) {
    LOADREGS(kb + 1);                 // kb even <= 14, so kb+1 <= 15 always valid
    COMPUTE(As0, Bs0);
    CVTWRITE(As1, Bs1);               // vmcnt wait lands here, after MFMAs issued
    __syncthreads();

    if (kb + 2 < KITERS) LOADREGS(kb + 2);
    COMPUTE(As1, Bs1);
    if (kb + 2 < KITERS) CVTWRITE(As0, Bs0);
    __syncthreads();
  }

#undef LOADREGS
#undef CVTWRITE
#undef COMPUTE

  // ---- coalesced epilogue (r12) -------------------------------------------
  // acc lane layout: tile row = wm*64 + mi*16 + kg*4 + q, col = wn*64 + ni*16 + fr.
  // 4 passes of 32 rows via [32][132] f32 LDS aliased onto As0 (16896 B).
  // Pass p: waves with wm==p>>1 write mi={2*(p&1),2*(p&1)+1} (+bias); then all
  // threads store: one dwordx4 instr = 32 lanes x 16 B = one FULL 512-B row
  // slice (4 whole 128-B lines, no RMW). 16 vector stores/thread vs 64 scalar.
  __syncthreads();                     // all COMPUTE reads of LDS done
  float* obuf = (float*)As0;           // 32*132*4 = 16896 B <= sizeof(As0)
  const int col0 = ntile * NTILE + wn * 64;
  float bv[4];
#pragma unroll
  for (int ni = 0; ni < 4; ++ni) bv[ni] = bias[s * DIM + col0 + ni * 16 + fr];

  const int rbase = tid >> 5;          // 0..7 : row within 8-row store group
  const int ch    = tid & 31;          // 16-B chunk within 512-B row

#pragma unroll
  for (int p = 0; p < 4; ++p) {
    if (wm == (p >> 1)) {
#pragma unroll
      for (int mh = 0; mh < 2; ++mh) {
        const int mi = (p & 1) * 2 + mh;
        const int lr = mi * 16 + kg * 4 - (p & 1) * 32;   // 0..28 local row base
#pragma unroll
        for (int q = 0; q < 4; ++q)
#pragma unroll
          for (int ni = 0; ni < 4; ++ni)
            obuf[(lr + q) * 132 + wn * 64 + ni * 16 + fr] = acc[mi][ni][q] + bv[ni];
      }
    }
    __syncthreads();
#pragma unroll
    for (int j = 0; j < 4; ++j) {
      const int lr = j * 8 + rbase;              // 0..31
      const int ml = p * 32 + lr;                // tile row
      if (ml < nrows) {
        const int orow = row_ids[ml];
        const floatx4 v = *(const floatx4*)&obuf[lr * 132 + ch * 4];
        *(floatx4*)&out[(size_t)orow * DIM + ntile * NTILE + ch * 4] = v;
      }
    }
    __syncthreads();
  }
}

extern "C" void kernel_launch(void* const* d_in, const int* in_sizes, int n_in,
                              void* d_out, int out_size, void* d_ws, size_t ws_size,
                              hipStream_t stream) {
  const float* x    = (const float*)d_in[0];
  const float* W    = (const float*)d_in[1];
  const float* b    = (const float*)d_in[2];
  const int*   sidx = (const int*)d_in[3];
  float* out = (float*)d_out;
  (void)d_ws; (void)ws_size;  // OFF-LIMITS: any ws touch => 512MiB re-poison
                              // fill (~80us) per iteration (r9 post-mortem)

  hipLaunchKernelGGL(gemm_kernel, dim3(NSESS * TPE * (DIM / NTILE)), dim3(256),
                     0, stream, x, W, b, sidx, out);
}